// Round 3
// baseline (1332.769 us; speedup 1.0000x reference)
//
#include <hip/hip_runtime.h>
#include <hip/hip_bf16.h>

using u32 = unsigned int;
using u16 = unsigned short;

#define NGR   512     // graphs
#define NF    128     // edge features
#define GF    64      // global features
#define HID   64
#define IN1   192     // GF + NF
#define NB    256     // stream blocks (1 per CU)
#define TT    128     // edges per LDS tile
#define NTHREADS 1024
#define NSLAB 16      // sharded accumulator tables
#define ROWI  132     // ints per graph row in a table (128 feats + count + pad)
#define SCALE     2097152.0f      // 2^21 fixed-point scale
#define INV_SCALE (1.0f/2097152.0f)

__global__ void zero_tab_kernel(int* __restrict__ tab, int n) {
    int i = blockIdx.x * blockDim.x + threadIdx.x;
    if (i < n) tab[i] = 0;
}

// One block per CU. Streams its contiguous edge chunk through LDS tiles
// (double-buffered); thread t accumulates (graph t>>1, half t&1) in 64 VGPRs.
__launch_bounds__(NTHREADS, 4)
__global__ void stream_scan_kernel(const float* __restrict__ edge_attr,
                                   const int* __restrict__ ei0,
                                   const int* __restrict__ batch,
                                   int* __restrict__ tab, int E) {
    extern __shared__ float smem[];
    float* tile0 = smem;                       // TT*NF floats (64 KB)
    float* tile1 = smem + TT * NF;             // 64 KB
    u16*   segb  = (u16*)(smem + 2 * TT * NF); // [2][TT]

    const int tid  = threadIdx.x;
    const int b    = blockIdx.x;
    const int myg  = tid >> 1;
    const int half = tid & 1;
    const int chunk = (E + NB - 1) / NB;
    const int start = b * chunk;
    const int end   = min(E, start + chunk);
    const int nt    = (end > start) ? (end - start + TT - 1) / TT : 0;

    float acc[64];
#pragma unroll
    for (int k = 0; k < 64; ++k) acc[k] = 0.0f;
    int cnt = 0;

    // stage tile 0 (each thread: 4 float4 = its slice of 128 rows)
    if (nt > 0) {
        const size_t tb = (size_t)start * NF;
#pragma unroll
        for (int p = 0; p < 4; ++p) {
            int erow = start + (p << 5) + (tid >> 5);
            if (erow < E) {
                float4 v = *(const float4*)(edge_attr + tb + (p << 12) + (tid << 2));
                *(float4*)(tile0 + (p << 12) + (tid << 2)) = v;
            }
        }
        if (tid < TT) {
            int e = start + tid;
            u16 s = 0xFFFFu;
            if (e < end) s = (u16)batch[ei0[e]];
            segb[tid] = s;
        }
    }
    __syncthreads();

    for (int t = 0; t < nt; ++t) {
        const int cur = t & 1;
        const float* tcur = cur ? tile1 : tile0;
        float*       tnxt = cur ? tile0 : tile1;
        const u16*   scur = segb + cur * TT;
        u16*         snxt = segb + (cur ^ 1) * TT;

        // issue next-tile global loads early (hide HBM latency under scan)
        float4 r0, r1, r2, r3;
        int ne = -1;
        const bool hn = (t + 1 < nt);
        const int nbase = start + (t + 1) * TT;
        int e0 = 0, e1 = 0, e2 = 0, e3 = 0;
        if (hn) {
            const size_t tb = (size_t)nbase * NF;
            e0 = nbase + 0 * 32 + (tid >> 5);
            e1 = nbase + 1 * 32 + (tid >> 5);
            e2 = nbase + 2 * 32 + (tid >> 5);
            e3 = nbase + 3 * 32 + (tid >> 5);
            if (e0 < E) r0 = *(const float4*)(edge_attr + tb + (0 << 12) + (tid << 2));
            if (e1 < E) r1 = *(const float4*)(edge_attr + tb + (1 << 12) + (tid << 2));
            if (e2 < E) r2 = *(const float4*)(edge_attr + tb + (2 << 12) + (tid << 2));
            if (e3 < E) r3 = *(const float4*)(edge_attr + tb + (3 << 12) + (tid << 2));
            if (tid < TT) { int e = nbase + tid; if (e < end) ne = ei0[e]; }
        }

        // scan current tile: per edge, exactly one wave runs the 2-lane body
#pragma unroll 1
        for (int i = 0; i < TT; ++i) {
            int s = (int)scur[i];
            if (__any(s == myg)) {
                if (s == myg) {
                    const float* row = tcur + (i << 7) + (half << 6);
#pragma unroll
                    for (int k = 0; k < 16; ++k) {
                        float4 v = *(const float4*)(row + (k << 2));
                        acc[4 * k + 0] += v.x; acc[4 * k + 1] += v.y;
                        acc[4 * k + 2] += v.z; acc[4 * k + 3] += v.w;
                    }
                    if (half == 0) ++cnt;
                }
            }
        }
        __syncthreads();
        if (hn) {
            if (e0 < E) *(float4*)(tnxt + (0 << 12) + (tid << 2)) = r0;
            if (e1 < E) *(float4*)(tnxt + (1 << 12) + (tid << 2)) = r1;
            if (e2 < E) *(float4*)(tnxt + (2 << 12) + (tid << 2)) = r2;
            if (e3 < E) *(float4*)(tnxt + (3 << 12) + (tid << 2)) = r3;
            if (tid < TT) snxt[tid] = (ne >= 0) ? (u16)batch[ne] : (u16)0xFFFFu;
        }
        __syncthreads();
    }

    // dump: fixed-point int32 atomics into this block's slab (order-independent
    // -> bitwise deterministic; |sum|*2^21 << 2^31)
    int* rowp = tab + ((size_t)(b & (NSLAB - 1)) * NGR + myg) * ROWI + (half << 6);
#pragma unroll
    for (int k = 0; k < 64; ++k) {
        int v = __float2int_rn(acc[k] * SCALE);
        atomicAdd(rowp + k, v);
    }
    if (half == 0) atomicAdd(tab + ((size_t)(b & (NSLAB - 1)) * NGR + myg) * ROWI + 128, cnt);
}

// Per-graph: integer-merge slabs (exact), mean, 2-layer MLP.
__global__ void final_kernel(const int* __restrict__ tab,
                             const float* __restrict__ u,
                             const float* __restrict__ W1,
                             const float* __restrict__ b1,
                             const float* __restrict__ W2,
                             const float* __restrict__ b2,
                             float* __restrict__ out) {
    __shared__ float sums[129];
    __shared__ float vin[IN1];
    __shared__ float hv[HID];
    const int g = blockIdx.x, t = threadIdx.x;   // 256 threads
    if (t < 129) {
        int isum = 0;
#pragma unroll
        for (int s = 0; s < NSLAB; ++s)
            isum += tab[((size_t)s * NGR + g) * ROWI + t];
        sums[t] = (float)isum;
    }
    __syncthreads();
    const float cnt = fmaxf(sums[128], 1.0f);
    if (t < GF) vin[t] = u[g * GF + t];
    if (t >= GF && t < IN1) vin[t] = (sums[t - GF] * INV_SCALE) / cnt;
    __syncthreads();
    if (t < HID) {
        float a = b1[t];
#pragma unroll
        for (int k = 0; k < IN1; ++k) a += vin[k] * W1[k * HID + t];
        hv[t] = fmaxf(a, 0.0f);
    }
    __syncthreads();
    if (t < GF) {
        float a = b2[t];
#pragma unroll
        for (int k = 0; k < HID; ++k) a += hv[k] * W2[k * GF + t];
        out[g * GF + t] = a;
    }
}

extern "C" void kernel_launch(void* const* d_in, const int* in_sizes, int n_in,
                              void* d_out, int out_size, void* d_ws, size_t ws_size,
                              hipStream_t stream) {
    // inputs: 0:x(unused) 1:edge_index[2,E] 2:edge_attr[E,128] 3:u[512,64]
    //         4:batch[50000] 5:W1[192,64] 6:b1[64] 7:W2[64,64] 8:b2[64]
    const int*   ei        = (const int*)d_in[1];
    const float* edge_attr = (const float*)d_in[2];
    const float* u         = (const float*)d_in[3];
    const int*   batch     = (const int*)d_in[4];
    const float* W1        = (const float*)d_in[5];
    const float* b1        = (const float*)d_in[6];
    const float* W2        = (const float*)d_in[7];
    const float* b2        = (const float*)d_in[8];
    float*       out       = (float*)d_out;

    const int E = in_sizes[1] / 2;
    const int* ei0 = ei;               // row 0 of edge_index

    int* tab = (int*)d_ws;             // [NSLAB][NGR][ROWI] ints = 4.3 MB
    const int tab_n = NSLAB * NGR * ROWI;

    zero_tab_kernel<<<(tab_n + 255) / 256, 256, 0, stream>>>(tab, tab_n);

    const size_t lds_bytes = (size_t)2 * TT * NF * sizeof(float) + 2 * TT * sizeof(u16);
    stream_scan_kernel<<<NB, NTHREADS, lds_bytes, stream>>>(edge_attr, ei0, batch, tab, E);

    final_kernel<<<NGR, 256, 0, stream>>>(tab, u, W1, b1, W2, b2, out);
}

// Round 4
// 369.150 us; speedup vs baseline: 3.6104x; 3.6104x over previous
//
#include <hip/hip_runtime.h>
#include <hip/hip_bf16.h>

typedef unsigned int u32;
typedef unsigned short u16;
typedef u32 u32x2 __attribute__((ext_vector_type(2)));
typedef u32 u32x4v __attribute__((ext_vector_type(4)));
typedef short short8 __attribute__((ext_vector_type(8)));
typedef float f32x4 __attribute__((ext_vector_type(4)));

#define NGR 512     // graphs
#define NF 128      // edge features
#define GF 64       // global features
#define HID 64
#define IN1 192
#define NB 256      // one block per CU
#define TE 128      // edges per staged tile
#define EPB 6250    // E / NB (E = 1,600,000)
#define NTILES 49   // ceil(6250/128)

__device__ __forceinline__ u16 f2bf(float x) {
    union { float f; u32 u; } a; a.f = x;
    u32 r = a.u + 0x7FFFu + ((a.u >> 16) & 1u);   // RNE
    return (u16)(r >> 16);
}

// LDS tile layout: [fb(8)][eb(32)][4][16] bf16 subtiles (row=edge, col=feat).
// ds_read_b64_tr_b16 with per-lane addr = subtile(2*g4)*128 + ln*8 delivers
// lane(g4,ln) elem j = attr[edge = w*32 + 8*g4 + j][feat = ft*16 + ln]
// = A-fragment slot k=8*g4+j of mfma_f32_16x16x32_bf16 (m=ln).  offset:128 -> k+4.

#define STAGE_LOAD(tile) do {                                                  \
    const int tb_ = (tile) * TE;                                               \
    _Pragma("unroll")                                                          \
    for (int p_ = 0; p_ < 4; ++p_) {                                           \
        int c_ = tid + p_ * 1024;                                              \
        int e_ = c_ >> 5, q_ = c_ & 31;                                        \
        int el_ = tb_ + e_;                                                    \
        float4 v_ = make_float4(0.f, 0.f, 0.f, 0.f);                           \
        if (el_ < EPB) v_ = *(const float4*)(edge_attr + (size_t)(estart + el_) * NF + q_ * 4); \
        pv[p_] = v_;                                                           \
    }                                                                          \
    psv = 0xFFFF;                                                              \
    if (tid < TE) { int el_ = tb_ + tid; if (el_ < EPB) psv = batch[ei0[estart + el_]]; } \
} while (0)

#define STAGE_WRITE(bi) do {                                                   \
    _Pragma("unroll")                                                          \
    for (int p_ = 0; p_ < 4; ++p_) {                                           \
        int c_ = tid + p_ * 1024;                                              \
        int e_ = c_ >> 5, q_ = c_ & 31;                                        \
        int f_ = q_ * 4;                                                       \
        u32 lo_ = (u32)f2bf(pv[p_].x) | ((u32)f2bf(pv[p_].y) << 16);           \
        u32 hi_ = (u32)f2bf(pv[p_].z) | ((u32)f2bf(pv[p_].w) << 16);           \
        u32x2 w_; w_.x = lo_; w_.y = hi_;                                      \
        int off_ = (((f_ >> 4) * 32 + (e_ >> 2)) * 128) + ((e_ & 3) * 32) + ((f_ & 15) * 2); \
        *(u32x2*)((char*)(&buf[bi][0]) + off_) = w_;                           \
    }                                                                          \
    if (tid < TE) segb[bi][tid] = (u16)psv;                                    \
} while (0)

#define PROCESS(bi) do {                                                       \
    const u32 base_ = (u32)(size_t)(&buf[bi][0]);                              \
    _Pragma("unroll 1")                                                        \
    for (int w_ = 0; w_ < 4; ++w_) {                                           \
        u32x4v sw_ = *(const u32x4v*)((const char*)(&segb[bi][0]) + w_ * 64 + g4 * 16); \
        union { u32x4v u; short8 s; } su0_, su1_;                              \
        const u32 t0_ = (u32)(gbase + ln), t1_ = t0_ + 16u;                    \
        _Pragma("unroll")                                                      \
        for (int i_ = 0; i_ < 4; ++i_) {                                       \
            u32 lo_ = sw_[i_] & 0xFFFFu, hi_ = sw_[i_] >> 16;                  \
            u32 a_ = 0u, b2_ = 0u;                                             \
            if (lo_ == t0_) { a_ |= 0x3F80u; ++cnt0; }                         \
            if (hi_ == t0_) { a_ |= 0x3F800000u; ++cnt0; }                     \
            if (lo_ == t1_) { b2_ |= 0x3F80u; ++cnt1; }                        \
            if (hi_ == t1_) { b2_ |= 0x3F800000u; ++cnt1; }                    \
            su0_.u[i_] = a_; su1_.u[i_] = b2_;                                 \
        }                                                                      \
        _Pragma("unroll")                                                      \
        for (int ph_ = 0; ph_ < 2; ++ph_) {                                    \
            u32x2 aL_[4], aH_[4];                                              \
            _Pragma("unroll")                                                  \
            for (int k_ = 0; k_ < 4; ++k_) {                                   \
                int ft_ = ph_ * 4 + k_;                                        \
                u32 ad_ = base_ + (u32)(((ft_ * 32 + w_ * 8 + 2 * g4) * 128) + ln * 8); \
                asm volatile("ds_read_b64_tr_b16 %0, %1" : "=v"(aL_[k_]) : "v"(ad_)); \
                asm volatile("ds_read_b64_tr_b16 %0, %1 offset:128" : "=v"(aH_[k_]) : "v"(ad_)); \
            }                                                                  \
            asm volatile("s_waitcnt lgkmcnt(0)");                              \
            __builtin_amdgcn_sched_barrier(0);                                 \
            _Pragma("unroll")                                                  \
            for (int k_ = 0; k_ < 4; ++k_) {                                   \
                int ft_ = ph_ * 4 + k_;                                        \
                union { u32x4v u; short8 s; } af_;                             \
                af_.u[0] = aL_[k_].x; af_.u[1] = aL_[k_].y;                    \
                af_.u[2] = aH_[k_].x; af_.u[3] = aH_[k_].y;                    \
                acc0[ft_] = __builtin_amdgcn_mfma_f32_16x16x32_bf16(af_.s, su0_.s, acc0[ft_], 0, 0, 0); \
                acc1[ft_] = __builtin_amdgcn_mfma_f32_16x16x32_bf16(af_.s, su1_.s, acc1[ft_], 0, 0, 0); \
            }                                                                  \
        }                                                                      \
    }                                                                          \
} while (0)

__launch_bounds__(1024, 1)
__global__ void stream_mfma_kernel(const float* __restrict__ edge_attr,
                                   const int* __restrict__ ei0,
                                   const int* __restrict__ batch,
                                   float* __restrict__ partial,
                                   float* __restrict__ cntp) {
    __shared__ __align__(16) u16 buf[2][8 * 32 * 64];   // 2 x 32 KB
    __shared__ __align__(16) u16 segb[2][TE];

    const int tid = threadIdx.x;
    const int b = blockIdx.x;
    const int wave = tid >> 6;
    const int lane = tid & 63;
    const int g4 = lane >> 4;
    const int ln = lane & 15;
    const int gbase = wave * 32;
    const int estart = b * EPB;

    f32x4 acc0[8], acc1[8];
#pragma unroll
    for (int i = 0; i < 8; ++i) {
        acc0[i] = (f32x4){0.f, 0.f, 0.f, 0.f};
        acc1[i] = (f32x4){0.f, 0.f, 0.f, 0.f};
    }
    u32 cnt0 = 0, cnt1 = 0;

    float4 pv[4];
    int psv;

    STAGE_LOAD(0);
    STAGE_WRITE(0);
    __syncthreads();

#pragma unroll 1
    for (int t = 0; t < NTILES; ++t) {
        const int cur = t & 1;
        if (t + 1 < NTILES) STAGE_LOAD(t + 1);
        PROCESS(cur);
        __syncthreads();
        if (t + 1 < NTILES) STAGE_WRITE(cur ^ 1);
        __syncthreads();
    }

    // counts: reduce across the 4 lane-groups (each counted its own k-slots)
    cnt0 += __shfl_xor((int)cnt0, 16, 64);
    cnt0 += __shfl_xor((int)cnt0, 32, 64);
    cnt1 += __shfl_xor((int)cnt1, 16, 64);
    cnt1 += __shfl_xor((int)cnt1, 32, 64);
    if (g4 == 0) {
        cntp[(size_t)b * NGR + gbase + ln] = (float)cnt0;
        cntp[(size_t)b * NGR + gbase + 16 + ln] = (float)cnt1;
    }

    // dump: C/D layout col=lane&15 (graph-low), row=(lane>>4)*4+reg (feat-low)
#pragma unroll
    for (int ft = 0; ft < 8; ++ft) {
        const int f0 = ft * 16 + g4 * 4;
        f32x4 v0 = acc0[ft];
        f32x4 v1 = acc1[ft];
        *(float4*)(partial + ((size_t)b * NGR + (gbase + ln)) * NF + f0) =
            make_float4(v0[0], v0[1], v0[2], v0[3]);
        *(float4*)(partial + ((size_t)b * NGR + (gbase + 16 + ln)) * NF + f0) =
            make_float4(v1[0], v1[1], v1[2], v1[3]);
    }
}

__global__ void final_kernel(const float* __restrict__ partial,
                             const float* __restrict__ cntp,
                             const float* __restrict__ u,
                             const float* __restrict__ W1,
                             const float* __restrict__ b1,
                             const float* __restrict__ W2,
                             const float* __restrict__ b2,
                             float* __restrict__ out) {
    __shared__ float vin[IN1];
    __shared__ float hv[HID];
    __shared__ f32x4 red[8][32];
    __shared__ float csh[256];
    const int g = blockIdx.x, t = threadIdx.x;   // 256 threads

    csh[t] = cntp[(size_t)t * NGR + g];

    const int chunk = t & 31, grp = t >> 5;
    f32x4 s = {0.f, 0.f, 0.f, 0.f};
#pragma unroll 4
    for (int k = 0; k < 32; ++k) {
        int slab = grp + k * 8;
        const float4 vv = *(const float4*)(partial + ((size_t)slab * NGR + g) * NF + chunk * 4);
        s[0] += vv.x; s[1] += vv.y; s[2] += vv.z; s[3] += vv.w;
    }
    red[grp][chunk] = s;
    __syncthreads();
    if (t < 128) csh[t] += csh[t + 128];
    __syncthreads();
    if (t < 64) csh[t] += csh[t + 64];
    __syncthreads();
    if (t < 32) csh[t] += csh[t + 32];
    __syncthreads();
    if (t < 16) csh[t] += csh[t + 16];
    __syncthreads();
    if (t < 8) csh[t] += csh[t + 8];
    __syncthreads();
    if (t < 4) csh[t] += csh[t + 4];
    __syncthreads();
    if (t < 2) csh[t] += csh[t + 2];
    __syncthreads();
    if (t < 1) csh[t] += csh[t + 1];
    __syncthreads();
    const float cnt = fmaxf(csh[0], 1.0f);
    const float inv = 1.0f / cnt;
    if (t < GF) vin[t] = u[g * GF + t];
    if (t < 32) {
        f32x4 m = red[0][t];
#pragma unroll
        for (int r = 1; r < 8; ++r) {
            f32x4 q = red[r][t];
            m[0] += q[0]; m[1] += q[1]; m[2] += q[2]; m[3] += q[3];
        }
        vin[GF + t * 4 + 0] = m[0] * inv;
        vin[GF + t * 4 + 1] = m[1] * inv;
        vin[GF + t * 4 + 2] = m[2] * inv;
        vin[GF + t * 4 + 3] = m[3] * inv;
    }
    __syncthreads();
    if (t < HID) {
        float a = b1[t];
#pragma unroll
        for (int k = 0; k < IN1; ++k) a += vin[k] * W1[k * HID + t];
        hv[t] = fmaxf(a, 0.0f);
    }
    __syncthreads();
    if (t < GF) {
        float a = b2[t];
#pragma unroll
        for (int k = 0; k < HID; ++k) a += hv[k] * W2[k * GF + t];
        out[g * GF + t] = a;
    }
}

extern "C" void kernel_launch(void* const* d_in, const int* in_sizes, int n_in,
                              void* d_out, int out_size, void* d_ws, size_t ws_size,
                              hipStream_t stream) {
    // inputs: 0:x(unused) 1:edge_index[2,E] 2:edge_attr[E,128] 3:u[512,64]
    //         4:batch[50000] 5:W1[192,64] 6:b1[64] 7:W2[64,64] 8:b2[64]
    const int*   ei        = (const int*)d_in[1];
    const float* edge_attr = (const float*)d_in[2];
    const float* u         = (const float*)d_in[3];
    const int*   batch     = (const int*)d_in[4];
    const float* W1        = (const float*)d_in[5];
    const float* b1        = (const float*)d_in[6];
    const float* W2        = (const float*)d_in[7];
    const float* b2        = (const float*)d_in[8];
    float*       out       = (float*)d_out;

    const int* ei0 = ei;   // row 0 of edge_index

    // workspace: partial[NB][NGR][NF] f32 (64 MB) | cntp[NB][NGR] f32 (512 KB)
    float* partial = (float*)d_ws;
    float* cntp    = partial + (size_t)NB * NGR * NF;

    stream_mfma_kernel<<<NB, 1024, 0, stream>>>(edge_attr, ei0, batch, partial, cntp);
    final_kernel<<<NGR, 256, 0, stream>>>(partial, cntp, u, W1, b1, W2, b2, out);
}